// Round 2
// baseline (587.711 us; speedup 1.0000x reference)
//
#include <hip/hip_runtime.h>

// LIF scan, two-phase checkpointed decomposition (bit-exact vs sequential):
//  Phase 1: 1 thread/row, v-only scan of L=1024, record v entering each of
//           16 chunks (64 steps) into d_ws. Loads only, register-dbuf prefetch.
//  Phase 2: 16 threads/row (32 waves/CU), each replays its chunk from the
//           checkpoint with the IDENTICAL f32 op sequence, writes z and s.
// Traffic: 128(MB p1 read) + 128+256(p2) = 512 MB -> ~81us floor @6.3TB/s.

constexpr int L_LEN  = 1024;
constexpr int CHUNK  = 64;
constexpr int NCHUNK = L_LEN / CHUNK;   // 16

#define ALPHA 0.7165313105737893f
#define OMA   (1.0f - 0.7165313105737893f)
#define THR   0.25f
#define BETA  10.0f

__global__ __launch_bounds__(64) void lif_phase1(
    const float* __restrict__ I, float* __restrict__ states, int nrows)
{
#pragma clang fp contract(off)
    int row = blockIdx.x * 64 + threadIdx.x;
    if (row >= nrows) return;

    const float4* in4 = reinterpret_cast<const float4*>(I) + (size_t)row * (L_LEN / 4);

    float st[NCHUNK];
    float v = 0.0f;

    float4 buf[8];
#pragma unroll
    for (int j = 0; j < 8; ++j) buf[j] = in4[j];

    const int nblk = L_LEN / 32;  // 32 blocks of 32 elems
    for (int blk = 0; blk < nblk; ++blk) {
        float4 nxt[8];
        if (blk + 1 < nblk) {
#pragma unroll
            for (int j = 0; j < 8; ++j) nxt[j] = in4[(blk + 1) * 8 + j];
        } else {
#pragma unroll
            for (int j = 0; j < 8; ++j) nxt[j] = make_float4(0.f, 0.f, 0.f, 0.f);
        }

        if ((blk & 1) == 0) st[blk >> 1] = v;   // state entering chunk blk/2

#pragma unroll
        for (int j = 0; j < 8; ++j) {
            float4 x = buf[j];
            float vp;
            vp = ALPHA * v + OMA * x.x;  v = (vp >= THR) ? 0.0f : vp;
            vp = ALPHA * v + OMA * x.y;  v = (vp >= THR) ? 0.0f : vp;
            vp = ALPHA * v + OMA * x.z;  v = (vp >= THR) ? 0.0f : vp;
            vp = ALPHA * v + OMA * x.w;  v = (vp >= THR) ? 0.0f : vp;
        }
#pragma unroll
        for (int j = 0; j < 8; ++j) buf[j] = nxt[j];
    }

    float4* sp = reinterpret_cast<float4*>(states) + (size_t)row * (NCHUNK / 4);
#pragma unroll
    for (int c = 0; c < NCHUNK / 4; ++c)
        sp[c] = make_float4(st[4*c], st[4*c+1], st[4*c+2], st[4*c+3]);
}

__global__ __launch_bounds__(256) void lif_phase2(
    const float* __restrict__ I, const float* __restrict__ states,
    float* __restrict__ Z, float* __restrict__ S, int nthreads)
{
#pragma clang fp contract(off)
    int tid = blockIdx.x * 256 + threadIdx.x;
    if (tid >= nthreads) return;

    int row = tid >> 4;        // NCHUNK = 16
    int c   = tid & 15;

    float v = states[tid];     // states[row*16 + c]

    size_t base = (size_t)row * (L_LEN / 4) + (size_t)c * (CHUNK / 4);
    const float4* in4 = reinterpret_cast<const float4*>(I) + base;
    float4*       z4  = reinterpret_cast<float4*>(Z) + base;
    float4*       s4  = reinterpret_cast<float4*>(S) + base;

#pragma unroll
    for (int t = 0; t < CHUNK / 4; ++t) {
        float4 x = in4[t];
        float4 zo, so;
        float vp;

        vp = ALPHA * v + OMA * x.x;
        zo.x = BETA * (vp - THR);
        so.x = (vp >= THR) ? 1.0f : 0.0f;
        v    = (vp >= THR) ? 0.0f : vp;

        vp = ALPHA * v + OMA * x.y;
        zo.y = BETA * (vp - THR);
        so.y = (vp >= THR) ? 1.0f : 0.0f;
        v    = (vp >= THR) ? 0.0f : vp;

        vp = ALPHA * v + OMA * x.z;
        zo.z = BETA * (vp - THR);
        so.z = (vp >= THR) ? 1.0f : 0.0f;
        v    = (vp >= THR) ? 0.0f : vp;

        vp = ALPHA * v + OMA * x.w;
        zo.w = BETA * (vp - THR);
        so.w = (vp >= THR) ? 1.0f : 0.0f;
        v    = (vp >= THR) ? 0.0f : vp;

        z4[t] = zo;
        s4[t] = so;
    }
}

// R1 fallback (single kernel, 1 thread/row) if workspace is too small.
__global__ __launch_bounds__(64) void lif_single(
    const float* __restrict__ I, float* __restrict__ Z,
    float* __restrict__ S, int nrows)
{
#pragma clang fp contract(off)
    int row = blockIdx.x * 64 + threadIdx.x;
    if (row >= nrows) return;

    const float4* in4 = reinterpret_cast<const float4*>(I) + (size_t)row * (L_LEN / 4);
    float4*       z4  = reinterpret_cast<float4*>(Z)       + (size_t)row * (L_LEN / 4);
    float4*       s4  = reinterpret_cast<float4*>(S)       + (size_t)row * (L_LEN / 4);

    float v = 0.0f;
#pragma unroll 8
    for (int t = 0; t < L_LEN / 4; ++t) {
        float4 x = in4[t];
        float4 zo, so;
        float vp;
        vp = ALPHA * v + OMA * x.x; zo.x = BETA*(vp-THR); so.x = (vp>=THR)?1.f:0.f; v = (vp>=THR)?0.f:vp;
        vp = ALPHA * v + OMA * x.y; zo.y = BETA*(vp-THR); so.y = (vp>=THR)?1.f:0.f; v = (vp>=THR)?0.f:vp;
        vp = ALPHA * v + OMA * x.z; zo.z = BETA*(vp-THR); so.z = (vp>=THR)?1.f:0.f; v = (vp>=THR)?0.f:vp;
        vp = ALPHA * v + OMA * x.w; zo.w = BETA*(vp-THR); so.w = (vp>=THR)?1.f:0.f; v = (vp>=THR)?0.f:vp;
        z4[t] = zo;
        s4[t] = so;
    }
}

extern "C" void kernel_launch(void* const* d_in, const int* in_sizes, int n_in,
                              void* d_out, int out_size, void* d_ws, size_t ws_size,
                              hipStream_t stream) {
    const float* I = (const float*)d_in[0];
    int n_elems = in_sizes[0];           // B*F*L = 33554432
    int nrows   = n_elems / L_LEN;       // 32768

    float* Z = (float*)d_out;
    float* S = (float*)d_out + (size_t)n_elems;

    size_t states_bytes = (size_t)nrows * NCHUNK * sizeof(float);  // 2 MB

    if (ws_size >= states_bytes) {
        float* states = (float*)d_ws;
        lif_phase1<<<(nrows + 63) / 64, 64, 0, stream>>>(I, states, nrows);
        int nthreads = nrows * NCHUNK;   // 524288
        lif_phase2<<<(nthreads + 255) / 256, 256, 0, stream>>>(I, states, Z, S, nthreads);
    } else {
        lif_single<<<(nrows + 63) / 64, 64, 0, stream>>>(I, Z, S, nrows);
    }
}